// Round 1
// baseline (2810.063 us; speedup 1.0000x reference)
//
#include <hip/hip_runtime.h>
#include <math.h>

// Problem constants (reference: B=8192, D=256, H=64)
#define Dn 256
#define Hn 64
#define BT 32   // batch rows per block

// ---------------------------------------------------------------------------
// Kernel 1: build masked, transposed weights
//   V1t[(i*Dn + j)*Hn + k] = W1[(i*Hn + k)*Dn + j] * sigmoid(adj[j*Dn+i]) * (j!=i)
// Tiled transpose through LDS for coalescing on both sides.
// grid: (Dn/64, Dn), block: 256
// ---------------------------------------------------------------------------
__global__ __launch_bounds__(256) void prep_v1t(const float* __restrict__ W1,
                                                const float* __restrict__ adj,
                                                float* __restrict__ V1t) {
    __shared__ float tile[64][65];   // +1 pad: conflict-free transpose
    const int i  = blockIdx.y;
    const int j0 = blockIdx.x * 64;
    const int t  = threadIdx.x;
    const int c  = t & 63;           // fast index (j on read, k on write)
    const int q  = t >> 6;           // 0..3

#pragma unroll
    for (int it = 0; it < 16; ++it) {
        int k = it * 4 + q;
        tile[k][c] = W1[((size_t)i * Hn + k) * Dn + (size_t)(j0 + c)];
    }
    __syncthreads();
#pragma unroll
    for (int it = 0; it < 16; ++it) {
        int jj = it * 4 + q;
        int j  = j0 + jj;
        float m = 0.0f;
        if (j != i) {
            float x = adj[(size_t)j * Dn + i];
            m = 1.0f / (1.0f + expf(-x));
        }
        V1t[((size_t)i * Dn + j) * Hn + c] = tile[c][jj] * m;
    }
}

// ---------------------------------------------------------------------------
// Kernel 2: sequential SCM unroll. One block = BT batch rows, all 256 steps.
// z kept in LDS transposed: zs[j][r]  (stride BT+4 = 36 floats -> b128-aligned,
// banks spread for the final transposed write-out).
// Thread map: ktid = t&31 -> k pair (2 hidden units), rtid = t>>5 -> 4 rows.
// grid: B/BT, block: 256
// ---------------------------------------------------------------------------
__global__ __launch_bounds__(256) void scm_main(const float* __restrict__ V1t,
                                                const float* __restrict__ b1,
                                                const float* __restrict__ W2,
                                                const float* __restrict__ b2,
                                                const float* __restrict__ log_sigma,
                                                const float* __restrict__ noise,
                                                float* __restrict__ out) {
    __shared__ float zs[Dn][BT + 4];
    const int t    = threadIdx.x;
    const int ktid = t & 31;         // hidden-pair index: k = 2*ktid, 2*ktid+1
    const int rtid = t >> 5;         // row quad: rows rtid*4 .. rtid*4+3
    const int k0   = ktid * 2;
    const size_t rowbase = (size_t)blockIdx.x * BT;

    for (int idx = t; idx < Dn * (BT + 4); idx += 256)
        (&zs[0][0])[idx] = 0.0f;
    __syncthreads();

    for (int i = 0; i < Dn; ++i) {
        // acc[kk][c]: hidden unit k0+kk, row rtid*4+c
        float a00 = 0.f, a01 = 0.f, a02 = 0.f, a03 = 0.f;
        float a10 = 0.f, a11 = 0.f, a12 = 0.f, a13 = 0.f;
        const float* vp = V1t + ((size_t)i * Dn) * Hn + k0;

        // Triangular inner product: z[:,j]==0 for j>=i and diag is masked.
#pragma unroll 4
        for (int j = 0; j < i; ++j) {
            float4 zv = *(const float4*)&zs[j][rtid * 4];
            float2 wv = *(const float2*)&vp[(size_t)j * Hn];
            a00 += zv.x * wv.x; a01 += zv.y * wv.x;
            a02 += zv.z * wv.x; a03 += zv.w * wv.x;
            a10 += zv.x * wv.y; a11 += zv.y * wv.y;
            a12 += zv.z * wv.y; a13 += zv.w * wv.y;
        }

        // Epilogue: h = acc + b1 ; silu(h) ; dot with W2 over k.
        const float b1a = b1[(size_t)i * Hn + k0];
        const float b1b = b1[(size_t)i * Hn + k0 + 1];
        const float w2a = W2[(size_t)i * Hn + k0];
        const float w2b = W2[(size_t)i * Hn + k0 + 1];

        float p[4];
        {
            float h0, h1;
            h0 = a00 + b1a; h1 = a10 + b1b;
            p[0] = (h0 / (1.0f + expf(-h0))) * w2a + (h1 / (1.0f + expf(-h1))) * w2b;
            h0 = a01 + b1a; h1 = a11 + b1b;
            p[1] = (h0 / (1.0f + expf(-h0))) * w2a + (h1 / (1.0f + expf(-h1))) * w2b;
            h0 = a02 + b1a; h1 = a12 + b1b;
            p[2] = (h0 / (1.0f + expf(-h0))) * w2a + (h1 / (1.0f + expf(-h1))) * w2b;
            h0 = a03 + b1a; h1 = a13 + b1b;
            p[3] = (h0 / (1.0f + expf(-h0))) * w2a + (h1 / (1.0f + expf(-h1))) * w2b;
        }

        // Reduce over the 32 ktid lanes (butterfly; stays within a 32-half).
#pragma unroll
        for (int m = 16; m >= 1; m >>= 1) {
#pragma unroll
            for (int c = 0; c < 4; ++c) p[c] += __shfl_xor(p[c], m);
        }

        if (ktid == 0) {
            const float bb2 = b2[i];
            const float sg  = expf(log_sigma[i]);
#pragma unroll
            for (int c = 0; c < 4; ++c) {
                int r = rtid * 4 + c;
                zs[i][r] = p[c] + bb2 + sg * noise[(rowbase + r) * Dn + i];
            }
        }
        __syncthreads();   // zs[i] visible before step i+1 reads it
    }

    // Write out: out[(rowbase+r)*Dn + j] = zs[j][r]; consecutive t -> consecutive j.
    for (int idx = t; idx < BT * Dn; idx += 256) {
        int r  = idx >> 8;          // idx / 256
        int jj = idx & 255;         // idx % 256
        out[(rowbase + r) * Dn + jj] = zs[jj][r];
    }
}

// ---------------------------------------------------------------------------
extern "C" void kernel_launch(void* const* d_in, const int* in_sizes, int n_in,
                              void* d_out, int out_size, void* d_ws, size_t ws_size,
                              hipStream_t stream) {
    const float* noise      = (const float*)d_in[0];   // [B, D]
    const float* adj_logits = (const float*)d_in[1];   // [D, D]
    const float* W1         = (const float*)d_in[2];   // [D, H, D]
    const float* b1         = (const float*)d_in[3];   // [D, H]
    const float* W2         = (const float*)d_in[4];   // [D, H]
    const float* b2         = (const float*)d_in[5];   // [D]
    const float* log_sigma  = (const float*)d_in[6];   // [D]
    float* out = (float*)d_out;

    const int B = in_sizes[0] / Dn;                    // 8192
    float* V1t = (float*)d_ws;                         // Dn*Dn*Hn floats = 16.8 MB

    dim3 g1(Dn / 64, Dn);
    prep_v1t<<<g1, 256, 0, stream>>>(W1, adj_logits, V1t);

    dim3 g2(B / BT);
    scm_main<<<g2, 256, 0, stream>>>(V1t, b1, W2, b2, log_sigma, noise, out);
}

// Round 2
// 424.744 us; speedup vs baseline: 6.6159x; 6.6159x over previous
//
#include <hip/hip_runtime.h>
#include <math.h>

#define Dn 256
#define Hn 64
#define BT 32

typedef __attribute__((ext_vector_type(8))) short short8;
typedef float floatx4 __attribute__((ext_vector_type(4)));

static __device__ __forceinline__ unsigned short f2bf(float x) {
    unsigned int u = __float_as_uint(x);
    unsigned int r = (u + 0x7fffu + ((u >> 16) & 1u)) >> 16;   // RNE
    return (unsigned short)r;
}

// ---------------------------------------------------------------------------
// prep_wb: build masked bf16 weights directly in MFMA B-fragment layout.
// Fragment (i, c, w, lane, e)  <->  kk = w*16 + (lane&15), j = c*32 + (lane>>4)*8 + e
// value = bf16( W1[i][kk][j] * sigmoid(adj[j][i]) * (j != i) )
// Wb flat offset (ushort): (((i*8 + c)*4 + w)*64 + lane)*8 + e   -> lane-coalesced 16B
// grid: (8, 256) = (c, i), block 256
// ---------------------------------------------------------------------------
__global__ __launch_bounds__(256) void prep_wb(const float* __restrict__ W1,
                                               const float* __restrict__ adj,
                                               unsigned short* __restrict__ Wb) {
    const int c = blockIdx.x, i = blockIdx.y;
    const int t = threadIdx.x;
    const int w = t >> 6, l = t & 63;
    const int kk = w * 16 + (l & 15);
    const int jb = c * 32 + ((l >> 4) & 3) * 8;
    const float* wp = W1 + ((size_t)i * Hn + kk) * Dn + jb;
    unsigned short v[8];
#pragma unroll
    for (int e = 0; e < 8; ++e) {
        int j = jb + e;
        float m = 0.f;
        if (j != i) m = 1.f / (1.f + __expf(-adj[(size_t)j * Dn + i]));
        v[e] = f2bf(wp[e] * m);
    }
    unsigned short* dst = Wb + ((((size_t)i * 8 + c) * 4 + w) * 64 + l) * 8;
    *(short8*)dst = *(const short8*)v;
}

// ---------------------------------------------------------------------------
// scm_main: sequential SCM, MFMA per step.
//   block = 32 batch rows, 256 threads = 4 waves; wave w owns hidden slice
//   kk in [16w, 16w+16).  Per step i: C[32 x 64] = zbf[32 x K] * Wb[i][K x 64],
//   K = 32*cc chunks (columns >= i are zero in zbf -> harmless).
//   A-fragments cached in registers per frozen 32-column chunk; only the
//   in-progress chunk re-read from LDS each step.
// grid: B/BT = 256, block 256
// ---------------------------------------------------------------------------
__global__ __launch_bounds__(256, 1) void scm_main(const unsigned short* __restrict__ Wb,
                                                   const float* __restrict__ b1,
                                                   const float* __restrict__ W2,
                                                   const float* __restrict__ b2,
                                                   const float* __restrict__ log_sigma,
                                                   const float* __restrict__ noise,
                                                   float* __restrict__ out) {
    __shared__ unsigned short zbf[BT][264];   // bf16 z history, row stride 264 (16B-aligned)
    __shared__ float ns[BT][257];             // staged noise (+1 pad: conflict-free column read)
    __shared__ float part[4][34];             // per-wave det partials
    __shared__ float sgv[Dn];
    __shared__ float b2v[Dn];

    const int t = threadIdx.x;
    const int w = t >> 6;        // wave id -> hidden slice
    const int l = t & 63;
    const int n = l & 15;        // MFMA n / A-m lane index
    const int q = l >> 4;        // quad
    const size_t rowbase = (size_t)blockIdx.x * BT;

    for (int idx = t; idx < BT * 264; idx += 256) (&zbf[0][0])[idx] = 0;
    {
        const float4* np4 = (const float4*)noise;
        for (int idx = t; idx < BT * (Dn / 4); idx += 256) {
            int r = idx >> 6, jq = idx & 63;
            float4 v = np4[(rowbase + r) * (Dn / 4) + jq];
            ns[r][jq * 4 + 0] = v.x; ns[r][jq * 4 + 1] = v.y;
            ns[r][jq * 4 + 2] = v.z; ns[r][jq * 4 + 3] = v.w;
        }
    }
    sgv[t] = __expf(log_sigma[t]);
    b2v[t] = b2[t];
    __syncthreads();

    short8 af0[8], af1[8];       // A-fragment register cache (rows 0-15 / 16-31)
#pragma unroll
    for (int c = 0; c < 8; ++c) { af0[c] = (short8)0; af1[c] = (short8)0; }

    const int kk = w * 16 + n;
    const unsigned short* wb_l = Wb + (size_t)w * 512 + (size_t)l * 8;

    for (int i = 0; i < Dn; ++i) {
        const int cc = (i + 31) >> 5;          // chunks covering [0, i)
        const int lc = (i - 1) >> 5;           // in-progress chunk (valid for i>=1)

        // per-step uniform-ish loads, issued early
        float b1v = b1[i * Hn + kk];
        float w2v = W2[i * Hn + kk];

        // B fragments: coalesced 16B/lane, up to 8 independent loads
        short8 bf[8];
        const unsigned short* wrow = wb_l + (size_t)i * 16384;
#pragma unroll
        for (int c = 0; c < 8; ++c)
            if (c < cc) bf[c] = *(const short8*)(wrow + (size_t)c * 2048);

        // refresh the in-progress A chunk from LDS (includes column i-1)
        if (i >= 1) {
#pragma unroll
            for (int c = 0; c < 8; ++c)
                if (c == lc) {
                    af0[c] = *(const short8*)&zbf[n][c * 32 + q * 8];
                    af1[c] = *(const short8*)&zbf[16 + n][c * 32 + q * 8];
                }
        }

        floatx4 acc0 = {0.f, 0.f, 0.f, 0.f};
        floatx4 acc1 = {0.f, 0.f, 0.f, 0.f};
#pragma unroll
        for (int c = 0; c < 8; ++c)
            if (c < cc) {
                acc0 = __builtin_amdgcn_mfma_f32_16x16x32_bf16(af0[c], bf[c], acc0, 0, 0, 0);
                acc1 = __builtin_amdgcn_mfma_f32_16x16x32_bf16(af1[c], bf[c], acc1, 0, 0, 0);
            }

        // epilogue: h = acc + b1; silu; * W2 -> partial det over this wave's 16 kk
        float d0[4], d1[4];
#pragma unroll
        for (int r = 0; r < 4; ++r) {
            float h0 = acc0[r] + b1v;
            float h1 = acc1[r] + b1v;
            d0[r] = __fdividef(h0, 1.f + __expf(-h0)) * w2v;
            d1[r] = __fdividef(h1, 1.f + __expf(-h1)) * w2v;
        }
#pragma unroll
        for (int m = 1; m <= 8; m <<= 1) {
#pragma unroll
            for (int r = 0; r < 4; ++r) {
                d0[r] += __shfl_xor(d0[r], m);
                d1[r] += __shfl_xor(d1[r], m);
            }
        }
        if (n == 0) {
#pragma unroll
            for (int r = 0; r < 4; ++r) {
                part[w][q * 4 + r]      = d0[r];   // rows 0..15
                part[w][16 + q * 4 + r] = d1[r];   // rows 16..31
            }
        }
        __syncthreads();
        if (t < BT) {
            int r = t;
            float z = part[0][r] + part[1][r] + part[2][r] + part[3][r]
                    + b2v[i] + sgv[i] * ns[r][i];
            zbf[r][i] = f2bf(z);
            out[(rowbase + r) * Dn + i] = z;       // fp32-exact output path
        }
        __syncthreads();
    }
}

// ---------------------------------------------------------------------------
extern "C" void kernel_launch(void* const* d_in, const int* in_sizes, int n_in,
                              void* d_out, int out_size, void* d_ws, size_t ws_size,
                              hipStream_t stream) {
    const float* noise      = (const float*)d_in[0];
    const float* adj_logits = (const float*)d_in[1];
    const float* W1         = (const float*)d_in[2];
    const float* b1         = (const float*)d_in[3];
    const float* W2         = (const float*)d_in[4];
    const float* b2         = (const float*)d_in[5];
    const float* log_sigma  = (const float*)d_in[6];
    float* out = (float*)d_out;

    const int B = in_sizes[0] / Dn;                 // 8192
    unsigned short* Wb = (unsigned short*)d_ws;     // 8.39 MB fragment-layout weights

    dim3 g1(8, Dn);
    prep_wb<<<g1, 256, 0, stream>>>(W1, adj_logits, Wb);

    dim3 g2(B / BT);
    scm_main<<<g2, 256, 0, stream>>>(Wb, b1, W2, b2, log_sigma, noise, out);
}

// Round 3
// 381.954 us; speedup vs baseline: 7.3571x; 1.1120x over previous
//
#include <hip/hip_runtime.h>
#include <math.h>

#define Dn 256
#define Hn 64

typedef __attribute__((ext_vector_type(8))) short short8;
typedef float floatx4 __attribute__((ext_vector_type(4)));

static __device__ __forceinline__ unsigned short f2bf(float x) {
    unsigned int u = __float_as_uint(x);
    unsigned int r = (u + 0x7fffu + ((u >> 16) & 1u)) >> 16;   // RNE
    return (unsigned short)r;
}

// ---------------------------------------------------------------------------
// prep_sgm: sgm[i*Dn + j] = sigmoid(adj[j*Dn + i]) * (j != i)
// grid 256 (i), block 256 (j)
// ---------------------------------------------------------------------------
__global__ __launch_bounds__(256) void prep_sgm(const float* __restrict__ adj,
                                                float* __restrict__ sgm) {
    const int i = blockIdx.x, j = threadIdx.x;
    float m = 0.f;
    if (j != i) m = 1.f / (1.f + __expf(-adj[(size_t)j * Dn + i]));
    sgm[(size_t)i * Dn + j] = m;
}

// ---------------------------------------------------------------------------
// prep_wb: masked bf16 weights in MFMA B-fragment layout (validated in R2).
// Fragment (i, c, nb, lane, e) <-> kk = nb*16 + (lane&15), j = c*32 + (lane>>4)*8 + e
// Wb offset (ushort): (((i*8 + c)*4 + nb)*64 + lane)*8 + e
// grid (8, 256) = (c, i), block 256
// ---------------------------------------------------------------------------
__global__ __launch_bounds__(256) void prep_wb(const float* __restrict__ W1,
                                               const float* __restrict__ sgm,
                                               unsigned short* __restrict__ Wb) {
    const int c = blockIdx.x, i = blockIdx.y;
    const int t = threadIdx.x;
    const int nb = t >> 6, l = t & 63;
    const int kk = nb * 16 + (l & 15);
    const int jb = c * 32 + ((l >> 4) & 3) * 8;
    const float* wp = W1 + ((size_t)i * Hn + kk) * Dn + jb;
    const float* sp = sgm + (size_t)i * Dn + jb;
    unsigned short v[8];
#pragma unroll
    for (int e = 0; e < 8; ++e) v[e] = f2bf(wp[e] * sp[e]);
    unsigned short* dst = Wb + ((((size_t)i * 8 + c) * 4 + nb) * 64 + l) * 8;
    *(short8*)dst = *(const short8*)v;
}

// ---------------------------------------------------------------------------
// prep_nst: nsT[d*B + b] = exp(log_sigma[d]) * noise[b*Dn + d]  (64x64 tiles)
// grid (B/64, Dn/64), block 256
// ---------------------------------------------------------------------------
__global__ __launch_bounds__(256) void prep_nst(const float* __restrict__ noise,
                                                const float* __restrict__ ls,
                                                float* __restrict__ nsT, int B) {
    __shared__ float tile[64][65];
    const int bi = blockIdx.x * 64, dj = blockIdx.y * 64;
    const int t = threadIdx.x, c = t & 63, rq = t >> 6;
#pragma unroll
    for (int it = 0; it < 16; ++it) {
        int b = bi + it * 4 + rq;
        tile[it * 4 + rq][c] = noise[(size_t)b * Dn + dj + c];
    }
    __syncthreads();
#pragma unroll
    for (int it = 0; it < 16; ++it) {
        int d = dj + it * 4 + rq;
        float sg = __expf(ls[d]);
        nsT[(size_t)d * B + bi + c] = tile[c][it * 4 + rq] * sg;
    }
}

// ---------------------------------------------------------------------------
// scm_main: barrier-free sequential SCM.
//   block = 128 threads = 2 waves; wave w owns rows blockIdx.x*32 + w*16 .. +15
//   and ALL 64 hidden units (4 N-tiles). Per step i:
//     C[16 x 64] = z[16 x K] * Wb[i][K x 64], K = 32*(sec+1) (zero-padded cols).
//   Frozen 32-col chunks cached in registers (af); in-progress chunk read from
//   wave-private LDS each step. B / biases / noise for step i+1 prefetched
//   before step i's epilogue. NO __syncthreads in the loop.
// grid: B/32, block 128
// ---------------------------------------------------------------------------
__global__ __launch_bounds__(128, 1) void scm_main(const unsigned short* __restrict__ Wb,
                                                   const float* __restrict__ b1,
                                                   const float* __restrict__ W2,
                                                   const float* __restrict__ b2,
                                                   const float* __restrict__ nsT,
                                                   float* __restrict__ out, int B) {
    __shared__ unsigned short zbf[32][264];   // bf16 z history; wave-private halves
    const int t = threadIdx.x;
    const int w = t >> 6, l = t & 63;
    const int n = l & 15, q = l >> 4;
    const int rowbase = blockIdx.x * 32 + w * 16;

    // zero this wave's z history (wave-private -> no barrier needed)
    for (int idx = l; idx < 16 * 132; idx += 64) {
        int r = idx / 132, cc = idx - r * 132;
        ((unsigned int*)zbf[w * 16 + r])[cc] = 0u;
    }

    const unsigned short* wb_l = Wb + (size_t)l * 8;
    const unsigned short* zrow_lds = &zbf[w * 16 + n][0];   // this lane's A-row

    short8 af[8];          // frozen A chunks
    short8 bf[8][4];       // B fragments for current step (chunk, ntile)
    float b1v[4], w2v[4], b2v;
    float4 nv;

    // preload step 0
    {
#pragma unroll
        for (int nb = 0; nb < 4; ++nb) bf[0][nb] = *(const short8*)(wb_l + nb * 512);
#pragma unroll
        for (int nb = 0; nb < 4; ++nb) {
            b1v[nb] = b1[nb * 16 + n];
            w2v[nb] = W2[nb * 16 + n];
        }
        nv  = *(const float4*)(nsT + rowbase + q * 4);
        b2v = b2[0];
    }

#pragma unroll
    for (int sec = 0; sec < 8; ++sec) {
        if (sec > 0) {
            // promote just-completed chunk into the register A-cache
            af[sec - 1] = *(const short8*)(zrow_lds + (sec - 1) * 32 + q * 8);
            // load this section's new B chunk for its first step
            const unsigned short* wbp = wb_l + (size_t)(sec * 32) * 16384 + sec * 2048;
#pragma unroll
            for (int nb = 0; nb < 4; ++nb) bf[sec][nb] = *(const short8*)(wbp + nb * 512);
        }
#pragma unroll 1
        for (int ii = 0; ii < 32; ++ii) {
            const int i = sec * 32 + ii;

            // in-progress A chunk (cols sec*32..i-1 valid, rest zero)
            short8 ain = *(const short8*)(zrow_lds + sec * 32 + q * 8);

            floatx4 zero4 = {0.f, 0.f, 0.f, 0.f};
            floatx4 acc[4];
#pragma unroll
            for (int nb = 0; nb < 4; ++nb) acc[nb] = zero4;

            // frozen chunks (register A-cache)
#pragma unroll
            for (int c = 0; c < 8; ++c)
                if (c < sec) {
#pragma unroll
                    for (int nb = 0; nb < 4; ++nb)
                        acc[nb] = __builtin_amdgcn_mfma_f32_16x16x32_bf16(af[c], bf[c][nb], acc[nb], 0, 0, 0);
                }
            // in-progress chunk (fresh from LDS; ds latency covered by frozen MFMAs)
#pragma unroll
            for (int nb = 0; nb < 4; ++nb)
                acc[nb] = __builtin_amdgcn_mfma_f32_16x16x32_bf16(ain, bf[sec][nb], acc[nb], 0, 0, 0);

            // save current-step epilogue params before prefetch overwrites them
            float b1c[4], w2c[4], nvr[4];
            float b2c = b2v;
#pragma unroll
            for (int nb = 0; nb < 4; ++nb) { b1c[nb] = b1v[nb]; w2c[nb] = w2v[nb]; }
            nvr[0] = nv.x; nvr[1] = nv.y; nvr[2] = nv.z; nvr[3] = nv.w;

            // prefetch step i+1 (clamped at the end; chunk sec+1 handled at
            // next section's top). Loads fly during the long epilogue below.
            {
                int ip = i + 1; if (ip > 255) ip = 255;
                const unsigned short* wbp = wb_l + (size_t)ip * 16384;
#pragma unroll
                for (int c = 0; c < 8; ++c)
                    if (c <= sec) {
#pragma unroll
                        for (int nb = 0; nb < 4; ++nb)
                            bf[c][nb] = *(const short8*)(wbp + c * 2048 + nb * 512);
                    }
#pragma unroll
                for (int nb = 0; nb < 4; ++nb) {
                    b1v[nb] = b1[ip * Hn + nb * 16 + n];
                    w2v[nb] = W2[ip * Hn + nb * 16 + n];
                }
                nv  = *(const float4*)(nsT + (size_t)ip * B + rowbase + q * 4);
                b2v = b2[ip];
            }

            // epilogue: h = acc + b1; silu; dot W2 over all 64 hidden
            float d[4];
#pragma unroll
            for (int r = 0; r < 4; ++r) {
                float s = 0.f;
#pragma unroll
                for (int nb = 0; nb < 4; ++nb) {
                    float h = acc[nb][r] + b1c[nb];
                    s += __fdividef(h, 1.f + __expf(-h)) * w2c[nb];
                }
                d[r] = s;
            }
            // reduce over the 16 n-lanes (within each 16-lane group)
#pragma unroll
            for (int m = 1; m <= 8; m <<= 1) {
#pragma unroll
                for (int r = 0; r < 4; ++r) d[r] += __shfl_xor(d[r], m);
            }
            // z for rows q*4+r (all lanes of group q agree)
            float z[4];
#pragma unroll
            for (int r = 0; r < 4; ++r) z[r] = d[r] + b2c + nvr[r];

            // broadcast: zrow = z of row (l&15)
            int srcl = ((l & 15) >> 2) << 4;
            float t0 = __shfl(z[0], srcl), t1 = __shfl(z[1], srcl);
            float t2 = __shfl(z[2], srcl), t3 = __shfl(z[3], srcl);
            float za = (l & 1) ? t1 : t0;
            float zb = (l & 1) ? t3 : t2;
            float zrow = (l & 2) ? zb : za;

            if (q == 0) {   // lanes 0..15 of the wave: row n
                zbf[w * 16 + n][i] = f2bf(zrow);
                out[(size_t)(rowbase + n) * Dn + i] = zrow;
            }
        }
    }
}

// ---------------------------------------------------------------------------
extern "C" void kernel_launch(void* const* d_in, const int* in_sizes, int n_in,
                              void* d_out, int out_size, void* d_ws, size_t ws_size,
                              hipStream_t stream) {
    const float* noise      = (const float*)d_in[0];
    const float* adj_logits = (const float*)d_in[1];
    const float* W1         = (const float*)d_in[2];
    const float* b1         = (const float*)d_in[3];
    const float* W2         = (const float*)d_in[4];
    const float* b2         = (const float*)d_in[5];
    const float* log_sigma  = (const float*)d_in[6];
    float* out = (float*)d_out;

    const int B = in_sizes[0] / Dn;                       // 8192
    // ws layout (16.78 MB total, matches R1's proven footprint):
    //   [0, 8.39M)      : Wb   (bf16 fragment weights)
    //   [8.39M, 16.78M) : nsT  (fp32 transposed scaled noise);
    //                     sgm (256 KB) transiently occupies its start.
    unsigned short* Wb  = (unsigned short*)d_ws;
    float*          nsT = (float*)((char*)d_ws + (size_t)Dn * Dn * Hn * 2);
    float*          sgm = nsT;   // consumed by prep_wb before prep_nst overwrites

    prep_sgm<<<dim3(Dn), 256, 0, stream>>>(adj_logits, sgm);
    prep_wb<<<dim3(8, Dn), 256, 0, stream>>>(W1, sgm, Wb);
    prep_nst<<<dim3(B / 64, Dn / 64), 256, 0, stream>>>(noise, log_sigma, nsT, B);
    scm_main<<<dim3(B / 32), 128, 0, stream>>>(Wb, b1, W2, b2, nsT, out, B);
}